// Round 7
// baseline (186.380 us; speedup 1.0000x reference)
//
#include <hip/hip_runtime.h>

// QuestionFlowLayer: out[i] = concat(q[i], mean(q[0:i])) for q [1024, 64, 1024] f32.
//
// Round 6 = Round 5 with the compile fix: __builtin_nontemporal_* requires a
// NATIVE vector type (ext_vector_type), not HIP_vector_type<float,4>.
//
//  - 16384 float4 columns; one thread each. 256 blocks x 64 threads = 1 wave
//    per CU across all 256 CUs.
//  - Per row, a wave touches 1 KB contiguous on the read and 2 x 1 KB on the
//    writes (vs 256 B grains in R1) -> 4x coarser DRAM row-buffer bursts.
//  - No LDS, no barriers (R2/R4: the per-step exchange tax loses to the pure
//    stream even at 2x occupancy).
//  - Non-temporal loads/stores: both streams are touch-once; input 268 MB >
//    256 MB L3 anyway.
//  - Unroll 16: ~16 KB loads + 32 KB stores in flight per wave >> ~10 KB
//    needed to cover ~1000-cycle HBM latency at 10.25 B/cyc/CU.
typedef float f32x4 __attribute__((ext_vector_type(4)));

constexpr unsigned N_TURNS  = 1024;
constexpr unsigned C4       = 16384;   // float4 columns (L*D/4)
constexpr unsigned OUT_ROW4 = 32768;   // float4 per output turn (2*L*D/4)

__global__ __launch_bounds__(64) void qflow_f4_scan(
        const f32x4* __restrict__ q, f32x4* __restrict__ out) {
    const unsigned c4 = blockIdx.x * 64u + threadIdx.x;  // [0, 16384)
    const unsigned l  = c4 >> 8;           // 256 float4 per l-row
    const unsigned d4 = c4 & 255u;         // float4 index within D

    const f32x4* qp = q + c4;                             // q[i] = qp[i*C4]
    f32x4* op = out + (size_t)l * 512u + d4;              // v at op[i*OUT_ROW4]
                                                          // avg at +256
    f32x4 run = (f32x4)(0.0f);

    #pragma unroll 16
    for (unsigned i = 0; i < N_TURNS; ++i) {
        f32x4 v = __builtin_nontemporal_load(qp + (size_t)i * C4);
        const float inv = (i == 0) ? 0.0f : __builtin_amdgcn_rcpf((float)i);
        f32x4 a = run * inv;
        __builtin_nontemporal_store(v, op + (size_t)i * OUT_ROW4);
        __builtin_nontemporal_store(a, op + (size_t)i * OUT_ROW4 + 256u);
        run += v;
    }
}

extern "C" void kernel_launch(void* const* d_in, const int* in_sizes, int n_in,
                              void* d_out, int out_size, void* d_ws, size_t ws_size,
                              hipStream_t stream) {
    const f32x4* q = (const f32x4*)d_in[0];
    f32x4* out = (f32x4*)d_out;
    qflow_f4_scan<<<C4 / 64, 64, 0, stream>>>(q, out);
}

// Round 8
// 165.816 us; speedup vs baseline: 1.1240x; 1.1240x over previous
//
#include <hip/hip_runtime.h>

// QuestionFlowLayer: out[i] = concat(q[i], mean(q[0:i])) for q [1024, 64, 1024] f32.
//
// Round 7: block-scan with register double-buffered prefetch, raw barriers.
//  - Block = 512 threads (8 waves) owns 64 consecutive scalar columns; wave w
//    handles a 16-row chunk per 128-row super-step (8 steps, fully unrolled
//    so all ping-pong indices are compile-time constants -- no scratch).
//  - Step s+1's 16 loads are issued BEFORE step s's sum/exchange/emit, so the
//    sum never waits on fresh loads (fixes R4's per-step latency bubble).
//  - Cross-wave prefix via 4 KB ping-pong LDS; raw s_barrier + lgkmcnt(0)
//    only -- vmcnt never drained, global traffic flows across barriers.
//  - No sched_barrier(0) (in R4 it pinned next-step loads below the barrier).
//  - Input read once (268 MB), output written once (537 MB).
constexpr unsigned N_TURNS = 1024;
constexpr unsigned D_MOD   = 1024;
constexpr unsigned COLS    = 65536;              // L*D scalar columns
constexpr unsigned OUT_ROW = 2u * 64 * D_MOD;    // floats per output turn

constexpr int WAVES = 8;
constexpr int RPW   = 16;                        // rows per wave per step
constexpr int ROWS_PER_STEP = WAVES * RPW;       // 128
constexpr int NSTEP = (int)N_TURNS / ROWS_PER_STEP; // 8

__global__ __launch_bounds__(512) void qflow_scan_r7(
        const float* __restrict__ q, float* __restrict__ out) {
    __shared__ float csum[2][WAVES][64];         // ping-pong exchange buffer

    const unsigned lane = threadIdx.x & 63u;
    const unsigned w    = threadIdx.x >> 6;      // wave id [0,8)
    const unsigned c    = blockIdx.x * 64u + lane;
    const unsigned l    = c >> 10;
    const unsigned d    = c & (D_MOD - 1u);

    const float* qp = q + c;                     // q[i][c] = qp[i*COLS]
    // +2048B bias: v at imm -2048, avg at imm +2048 from one address.
    float* opb = out + (size_t)l * (2u * D_MOD) + d + 512u;

    float v[2][RPW];
    float superPrefix = 0.0f;

    // Prefetch step 0 into buffer 0.
    {
        const unsigned base = w * RPW;
        #pragma unroll
        for (int j = 0; j < RPW; ++j)
            v[0][j] = qp[(size_t)(base + j) * COLS];
    }

    #pragma unroll
    for (int s = 0; s < NSTEP; ++s) {            // fully unrolled: s, pb static
        const int pb = s & 1;

        // Issue next step's loads first (latency hidden under this step).
        if (s + 1 < NSTEP) {
            const unsigned nbase = (unsigned)(s + 1) * ROWS_PER_STEP + w * RPW;
            #pragma unroll
            for (int j = 0; j < RPW; ++j)
                v[pb ^ 1][j] = qp[(size_t)(nbase + j) * COLS];
        }

        // Chunk sum of current buffer (its loads are a full step old).
        float chunk = 0.0f;
        #pragma unroll
        for (int j = 0; j < RPW; ++j) chunk += v[pb][j];

        csum[pb][w][lane] = chunk;
        asm volatile("s_waitcnt lgkmcnt(0)" ::: "memory");
        __builtin_amdgcn_s_barrier();            // LDS-only rendezvous

        float run = superPrefix;
        float total = 0.0f;
        #pragma unroll
        for (int w2 = 0; w2 < WAVES; ++w2) {
            float t = csum[pb][w2][lane];
            total += t;
            if ((unsigned)w2 < w) run += t;      // wave-uniform predicate
        }

        const unsigned base = (unsigned)s * ROWS_PER_STEP + w * RPW;
        #pragma unroll
        for (int j = 0; j < RPW; ++j) {
            const unsigned i = base + j;
            const float inv = (i == 0) ? 0.0f : __builtin_amdgcn_rcpf((float)i);
            const float avg = run * inv;
            const size_t ob = (size_t)i * OUT_ROW;
            opb[ob - 512] = v[pb][j];            // out[i][l][d]
            opb[ob + 512] = avg;                 // out[i][l][D+d]
            run += v[pb][j];
        }
        superPrefix += total;
    }
}

extern "C" void kernel_launch(void* const* d_in, const int* in_sizes, int n_in,
                              void* d_out, int out_size, void* d_ws, size_t ws_size,
                              hipStream_t stream) {
    const float* q = (const float*)d_in[0];
    float* out = (float*)d_out;
    qflow_scan_r7<<<COLS / 64, 512, 0, stream>>>(q, out);
}

// Round 9
// 146.035 us; speedup vs baseline: 1.2763x; 1.1355x over previous
//
#include <hip/hip_runtime.h>

// QuestionFlowLayer: out[i] = concat(q[i], mean(q[0:i])) for q [1024, 64, 1024] f32.
//
// Round 8: exact R1 structure (the 153.6 us champion: one thread per scalar
// column, 4 waves/CU, barrier-free serial scan, minimal 805 MB traffic) with
// ONE isolated change: non-temporal loads/stores. Both streams are touch-once
// (input 268 MB, output 537 MB streaming through a 256 MB L3 with zero reuse),
// so skipping L2/L3 allocation removes any write-allocate / thrash cost.
// R6's NT test was confounded by 1-wave/CU occupancy; this is the clean A/B.
constexpr unsigned N_TURNS = 1024;
constexpr unsigned D_MOD   = 1024;
constexpr unsigned COLS    = 65536;                    // L*D scalar columns
constexpr unsigned ROW_STRIDE_OUT = 2u * D_MOD * 64u;  // floats per turn in out

__global__ __launch_bounds__(256) void qflow_scan_nt(
        const float* __restrict__ q, float* __restrict__ out) {
    unsigned c = blockIdx.x * 256u + threadIdx.x;   // column index [0, 65536)
    unsigned l = c >> 10;
    unsigned d = c & (D_MOD - 1u);

    const float* qp = q + c;                        // q[i][c] = qp[i*COLS]
    float* op = out + (size_t)l * (2u * D_MOD) + d; // out[i][l][d] = op[i*ROW]
    float run = 0.0f;
    #pragma unroll 32
    for (unsigned i = 0; i < N_TURNS; ++i) {
        float v = __builtin_nontemporal_load(qp + (size_t)i * COLS);
        float inv = (i == 0) ? 0.0f : __builtin_amdgcn_rcpf((float)i);
        float avg = run * inv;
        size_t ob = (size_t)i * ROW_STRIDE_OUT;
        __builtin_nontemporal_store(v, op + ob);
        __builtin_nontemporal_store(avg, op + ob + D_MOD);
        run += v;
    }
}

extern "C" void kernel_launch(void* const* d_in, const int* in_sizes, int n_in,
                              void* d_out, int out_size, void* d_ws, size_t ws_size,
                              hipStream_t stream) {
    const float* q = (const float*)d_in[0];
    float* out = (float*)d_out;
    qflow_scan_nt<<<COLS / 256, 256, 0, stream>>>(q, out);
}